// Round 7
// baseline (285.350 us; speedup 1.0000x reference)
//
#include <hip/hip_runtime.h>
#include <cstdint>

#define TAU_INV 5.0f
#define L2E 1.4426950408889634f

using ushort = unsigned short;
typedef __attribute__((ext_vector_type(8))) short s16x8;
typedef __attribute__((ext_vector_type(4))) float f32x4;

static __device__ __forceinline__ ushort f2bf(float x) {
  unsigned u = __float_as_uint(x);
  return (ushort)((u + 0x7fffu + ((u >> 16) & 1u)) >> 16);
}

static __device__ __forceinline__ float fexp2(float x) {
#if __has_builtin(__builtin_amdgcn_exp2f)
  return __builtin_amdgcn_exp2f(x);
#else
  return exp2f(x);
#endif
}

static __device__ __forceinline__ void gload_lds16(const void* g, void* l) {
  __builtin_amdgcn_global_load_lds(
      reinterpret_cast<const __attribute__((address_space(1))) void*>(
          reinterpret_cast<uintptr_t>(g)),
      reinterpret_cast<__attribute__((address_space(3))) void*>(
          (unsigned)reinterpret_cast<uintptr_t>(l)),
      16, 0, 0);
}

// bijective XCD-chunked swizzle of the (y*gx+x) tile space (m204 formula)
static __device__ __forceinline__ void xcd_swizzle(int gx, int gy, int& bx, int& by) {
  int nwg = gx * gy;
  int flat = by * gx + bx;
  int q = nwg >> 3, r = nwg & 7;
  int xcd = flat & 7, sl = flat >> 3;
  int tile = (xcd < r ? xcd * (q + 1) : r * (q + 1) + (xcd - r) * q) + sl;
  by = tile / gx;
  bx = tile - by * gx;
}

// ---------------- fused f32->bf16 convert + partial channel pool ----------------
__global__ void k_cvt_pool(const float* __restrict__ feat, ushort* __restrict__ obf,
                           float* __restrict__ gpart) {
  int b = blockIdx.y, pc = blockIdx.x, t = threadIdx.x;
  const float* fp = feat + ((size_t)b * 784 + (size_t)pc * 7) * 1024;
  ushort* op = obf + ((size_t)b * 784 + (size_t)pc * 7) * 1024;
  float4 acc = {0.f, 0.f, 0.f, 0.f};
#pragma unroll
  for (int p = 0; p < 7; ++p) {
    float4 v = ((const float4*)(fp + (size_t)p * 1024))[t];
    acc.x += v.x; acc.y += v.y; acc.z += v.z; acc.w += v.w;
    ushort4 r;
    r.x = f2bf(v.x); r.y = f2bf(v.y); r.z = f2bf(v.z); r.w = f2bf(v.w);
    ((ushort4*)(op + (size_t)p * 1024))[t] = r;
  }
  ((float4*)(gpart + ((size_t)b * 112 + pc) * 1024))[t] = acc;
}

__global__ void k_gpool_fin(const float* __restrict__ gpart, float* __restrict__ g) {
  int idx = blockIdx.x * 256 + threadIdx.x;
  int b = idx >> 10, c = idx & 1023;
  float s = 0.f;
#pragma unroll 4
  for (int pc = 0; pc < 112; ++pc) s += gpart[((size_t)b * 112 + pc) * 1024 + c];
  g[idx] = s * (1.0f / 784.0f);
}

__global__ void k_dense1_part(const float* __restrict__ g, const float* __restrict__ W,
                              float* __restrict__ part1) {
  int d = blockIdx.x * 256 + threadIdx.x;
  int k0 = blockIdx.y * 64;
  __shared__ float gs[512];
  for (int i = threadIdx.x; i < 512; i += 256) gs[i] = g[(i >> 6) * 1024 + k0 + (i & 63)];
  __syncthreads();
  float acc[8] = {};
  for (int kk = 0; kk < 64; ++kk) {
    float w = W[(size_t)(k0 + kk) * 2048 + d];
#pragma unroll
    for (int b = 0; b < 8; ++b) acc[b] += gs[b * 64 + kk] * w;
  }
#pragma unroll
  for (int b = 0; b < 8; ++b) part1[((size_t)blockIdx.y * 8 + b) * 2048 + d] = acc[b];
}

__global__ void k_dense1_fin(const float* __restrict__ part1, const float* __restrict__ bias,
                             float* __restrict__ h) {
  int idx = blockIdx.x * 256 + threadIdx.x;
  int b = idx >> 11, d = idx & 2047;
  float s = bias[d];
#pragma unroll
  for (int ks = 0; ks < 16; ++ks) s += part1[((size_t)ks * 8 + b) * 2048 + d];
  h[idx] = fmaxf(s, 0.f);
}

__global__ void k_dense2_part(const float* __restrict__ h, const float* __restrict__ W2,
                              float* __restrict__ part2) {
  int d = threadIdx.x;
  int k0 = blockIdx.x * 64;
  __shared__ float hs[512];
  for (int i = threadIdx.x; i < 512; i += 128) hs[i] = h[(i >> 6) * 2048 + k0 + (i & 63)];
  __syncthreads();
  float acc[8] = {};
  for (int kk = 0; kk < 64; ++kk) {
    float w = W2[(size_t)(k0 + kk) * 128 + d];
#pragma unroll
    for (int b = 0; b < 8; ++b) acc[b] += hs[b * 64 + kk] * w;
  }
#pragma unroll
  for (int b = 0; b < 8; ++b) part2[((size_t)blockIdx.x * 8 + b) * 128 + d] = acc[b];
}

__global__ void k_head_fin(const float* __restrict__ p2q, const float* __restrict__ p2k,
                           const float* __restrict__ bq, const float* __restrict__ bk,
                           float* __restrict__ qg, float* __restrict__ kg,
                           float* __restrict__ lpos) {
  int b = blockIdx.x, lane = threadIdx.x;
  float q0 = bq[lane], q1 = bq[lane + 64];
  float k0 = bk[lane], k1 = bk[lane + 64];
#pragma unroll
  for (int s = 0; s < 32; ++s) {
    size_t base = ((size_t)s * 8 + b) * 128;
    q0 += p2q[base + lane]; q1 += p2q[base + lane + 64];
    k0 += p2k[base + lane]; k1 += p2k[base + lane + 64];
  }
  float sq = q0 * q0 + q1 * q1, sk = k0 * k0 + k1 * k1;
#pragma unroll
  for (int d = 1; d < 64; d <<= 1) { sq += __shfl_xor(sq, d); sk += __shfl_xor(sk, d); }
  float rq = 1.0f / sqrtf(fmaxf(sq, 1e-12f));
  float rk = 1.0f / sqrtf(fmaxf(sk, 1e-12f));
  q0 *= rq; q1 *= rq; k0 *= rk; k1 *= rk;
  qg[b * 128 + lane] = q0; qg[b * 128 + 64 + lane] = q1;
  kg[b * 128 + lane] = k0; kg[b * 128 + 64 + lane] = k1;
  float lp = q0 * k0 + q1 * k1;
#pragma unroll
  for (int d = 1; d < 64; d <<= 1) lp += __shfl_xor(lp, d);
  if (lane == 0) lpos[b] = lp;
}

// ---------------- transpose + convert ----------------
__global__ void k_transpose_cvt(const float* __restrict__ W, ushort* __restrict__ Wt, int K, int N) {
  __shared__ float tile[32][33];
  int n0 = blockIdx.x * 32, k0 = blockIdx.y * 32;
  int tx = threadIdx.x & 31, ty = threadIdx.x >> 5;
#pragma unroll
  for (int i = 0; i < 32; i += 8)
    tile[ty + i][tx] = W[(size_t)(k0 + ty + i) * N + n0 + tx];
  __syncthreads();
#pragma unroll
  for (int i = 0; i < 32; i += 8)
    Wt[(size_t)(n0 + ty + i) * K + k0 + tx] = f2bf(tile[tx][ty + i]);
}

// ============ 256x256 8-wave 4-phase GEMM (E1): C = relu(A @ B^T + bias) -> bf16 ============
// A[M,K], B[N,K] bf16; dbuf LDS 128KB; per-wave out 128x64; phase-split + setprio.
__global__ __launch_bounds__(512, 2) void k_gemm256(
    const ushort* __restrict__ A, const ushort* __restrict__ B,
    const float* __restrict__ bias, ushort* __restrict__ O,
    int Mvalid, int K, int ldOut) {
  extern __shared__ unsigned char smem[];
  const int tid = threadIdx.x;
  int bx = blockIdx.x, by = blockIdx.y;
  xcd_swizzle(gridDim.x, gridDim.y, bx, by);
  const int mBase = by * 256, nBase = bx * 256;
  const int lane = tid & 63;
  const int wid_u = __builtin_amdgcn_readfirstlane(tid >> 6);
  const int wm = wid_u >> 2, wn = wid_u & 3;       // 2M x 4N waves
  const int lg = lane >> 4, li = lane & 15;
  const int lrow = lane >> 3, lchunk = lane & 7;
  const int gc = (lchunk ^ lrow) << 3;             // swizzled source chunk (elements)
  const int qb = wm * 2 + (wn & 1);                // B-quarter of this wave
  const int hB = wn >> 1;                          // B-half this wave reads/stages

  // staging sources + wave-uniform LDS dests (A: half wm, quarter wn; B: half hB, quarter qb)
  const ushort* aSrc[4]; const ushort* bSrc[4];
  unsigned aDst[4], bDst[4];
#pragma unroll
  for (int j = 0; j < 4; ++j) {
    int r2a = wn * 32 + j * 8 + lrow;
    int ga = mBase + wm * 128 + r2a; ga = ga < Mvalid ? ga : Mvalid - 1;
    aSrc[j] = A + (size_t)ga * K + gc;
    aDst[j] = (unsigned)(wm * 16384 + (wn * 32 + j * 8) * 128);
    int r2b = qb * 32 + j * 8 + lrow;
    int gb = nBase + hB * 128 + r2b;
    bSrc[j] = B + (size_t)gb * K + gc;
    bDst[j] = (unsigned)(32768 + hB * 16384 + (qb * 32 + j * 8) * 128);
  }

  f32x4 acc[8][4] = {};
  const int nt = K >> 6;

  auto ISSUE_A = [&](unsigned nb, int ko) {
#pragma unroll
    for (int j = 0; j < 4; ++j) gload_lds16(aSrc[j] + ko, smem + nb + aDst[j]);
  };
  auto ISSUE_B = [&](unsigned nb, int ko) {
#pragma unroll
    for (int j = 0; j < 4; ++j) gload_lds16(bSrc[j] + ko, smem + nb + bDst[j]);
  };

  ISSUE_A(0, 0); ISSUE_B(0, 0);
  __syncthreads();

  for (int t = 0; t < nt; ++t) {
    const unsigned bb = (unsigned)(t & 1) * 65536u;
    const unsigned nb = bb ^ 65536u;
    const bool pf = (t + 1 < nt);
    const int ko = (t + 1) << 6;
    const unsigned char* Ah = smem + bb + wm * 16384;
    const unsigned char* Bh = smem + bb + 32768 + hB * 16384;

    s16x8 bf[4][2];
    s16x8 af0[2][2], af1[2][2];

    // ---- phase 0: read all B frags + A frags mi=0,1; prefetch A(t+1)
    if (pf) ISSUE_A(nb, ko);
#pragma unroll
    for (int ni = 0; ni < 4; ++ni) {
      int r2 = (wn & 1) * 64 + ni * 16 + li;
#pragma unroll
      for (int ks = 0; ks < 2; ++ks)
        bf[ni][ks] = *(const s16x8*)(const void*)(Bh + r2 * 128 + (((ks * 4 + lg) ^ (r2 & 7)) << 4));
    }
#pragma unroll
    for (int e = 0; e < 2; ++e) {
      int r2 = e * 16 + li;
#pragma unroll
      for (int ks = 0; ks < 2; ++ks)
        af0[e][ks] = *(const s16x8*)(const void*)(Ah + r2 * 128 + (((ks * 4 + lg) ^ (r2 & 7)) << 4));
    }
    __builtin_amdgcn_s_barrier();
    __builtin_amdgcn_s_setprio(1);
#pragma unroll
    for (int e = 0; e < 2; ++e)
#pragma unroll
      for (int ni = 0; ni < 4; ++ni)
#pragma unroll
        for (int ks = 0; ks < 2; ++ks)
          acc[e][ni] = __builtin_amdgcn_mfma_f32_16x16x32_bf16(af0[e][ks], bf[ni][ks], acc[e][ni], 0, 0, 0);
    __builtin_amdgcn_s_setprio(0);
    __builtin_amdgcn_s_barrier();

    // ---- phase 1: A frags mi=2,3; prefetch B(t+1)
    if (pf) ISSUE_B(nb, ko);
#pragma unroll
    for (int e = 0; e < 2; ++e) {
      int r2 = (2 + e) * 16 + li;
#pragma unroll
      for (int ks = 0; ks < 2; ++ks)
        af1[e][ks] = *(const s16x8*)(const void*)(Ah + r2 * 128 + (((ks * 4 + lg) ^ (r2 & 7)) << 4));
    }
    __builtin_amdgcn_s_barrier();
    __builtin_amdgcn_s_setprio(1);
#pragma unroll
    for (int e = 0; e < 2; ++e)
#pragma unroll
      for (int ni = 0; ni < 4; ++ni)
#pragma unroll
        for (int ks = 0; ks < 2; ++ks)
          acc[2 + e][ni] = __builtin_amdgcn_mfma_f32_16x16x32_bf16(af1[e][ks], bf[ni][ks], acc[2 + e][ni], 0, 0, 0);
    __builtin_amdgcn_s_setprio(0);
    __builtin_amdgcn_s_barrier();

    // ---- phase 2: A frags mi=4,5
#pragma unroll
    for (int e = 0; e < 2; ++e) {
      int r2 = (4 + e) * 16 + li;
#pragma unroll
      for (int ks = 0; ks < 2; ++ks)
        af0[e][ks] = *(const s16x8*)(const void*)(Ah + r2 * 128 + (((ks * 4 + lg) ^ (r2 & 7)) << 4));
    }
    __builtin_amdgcn_s_barrier();
    __builtin_amdgcn_s_setprio(1);
#pragma unroll
    for (int e = 0; e < 2; ++e)
#pragma unroll
      for (int ni = 0; ni < 4; ++ni)
#pragma unroll
        for (int ks = 0; ks < 2; ++ks)
          acc[4 + e][ni] = __builtin_amdgcn_mfma_f32_16x16x32_bf16(af0[e][ks], bf[ni][ks], acc[4 + e][ni], 0, 0, 0);
    __builtin_amdgcn_s_setprio(0);
    __builtin_amdgcn_s_barrier();

    // ---- phase 3: A frags mi=6,7; tile-boundary drain
#pragma unroll
    for (int e = 0; e < 2; ++e) {
      int r2 = (6 + e) * 16 + li;
#pragma unroll
      for (int ks = 0; ks < 2; ++ks)
        af1[e][ks] = *(const s16x8*)(const void*)(Ah + r2 * 128 + (((ks * 4 + lg) ^ (r2 & 7)) << 4));
    }
    __builtin_amdgcn_s_barrier();
    __builtin_amdgcn_s_setprio(1);
#pragma unroll
    for (int e = 0; e < 2; ++e)
#pragma unroll
      for (int ni = 0; ni < 4; ++ni)
#pragma unroll
        for (int ks = 0; ks < 2; ++ks)
          acc[6 + e][ni] = __builtin_amdgcn_mfma_f32_16x16x32_bf16(af1[e][ks], bf[ni][ks], acc[6 + e][ni], 0, 0, 0);
    __builtin_amdgcn_s_setprio(0);
    __syncthreads();   // drains vmcnt(0)+lgkmcnt(0): next buffer fully staged for all waves
  }

  // epilogue: bias + relu + bf16 store, row-masked (N always full here)
#pragma unroll
  for (int ni = 0; ni < 4; ++ni) {
    int c = nBase + wn * 64 + ni * 16 + li;
    float bv = bias[c];
#pragma unroll
    for (int mi = 0; mi < 8; ++mi) {
#pragma unroll
      for (int rg = 0; rg < 4; ++rg) {
        int r = mBase + wm * 128 + mi * 16 + lg * 4 + rg;
        if (r < Mvalid) {
          float v = fmaxf(acc[mi][ni][rg] + bv, 0.f);
          O[(size_t)r * ldOut + c] = f2bf(v);
        }
      }
    }
  }
}

// ---------------- MFMA GEMM: 128x128 tile, BK=64, double-buffered 2-phase ----------------
// EPI 2: per-row sum(exp(acc*scale)) partials (max-free)
// EPI 3: per-row (max,argmax) EPI 4: raw f32 at slice offset bz*ntiles
template <int EPI>
__global__ __launch_bounds__(256) void k_gemm_abt(
    const ushort* __restrict__ A, const ushort* __restrict__ B,
    const float* __restrict__ bias, void* __restrict__ o0, void* __restrict__ o1,
    int Mvalid, int Nvalid, int Kloop, int lda, int ldb, int ldOut, int ntiles,
    float scale, long sA, long sB) {
  __shared__ unsigned char smem[65536];
  const int tid = threadIdx.x;
  int bx = blockIdx.x, by = blockIdx.y;
  const int bz = blockIdx.z;
  xcd_swizzle(gridDim.x, gridDim.y, bx, by);
  const ushort* Ab = A + (size_t)bz * sA;
  const ushort* Bb = B + (size_t)bz * sB;
  const int mBase = by * 128, nBase = bx * 128;
  const int lane = tid & 63;
  const int wid = tid >> 6;
  const int wid_u = __builtin_amdgcn_readfirstlane(wid);
  const int wm = wid >> 1, wn = wid & 1;
  const int lg = lane >> 4, li = lane & 15;
  const int lrow = lane >> 3, lchunk = lane & 7;

  const ushort* aSrc[4];
  const ushort* bSrc[4];
  int ldsOff[4];
#pragma unroll
  for (int j = 0; j < 4; ++j) {
    int r = wid_u * 32 + j * 8 + lrow;
    int gc = (lchunk ^ lrow) << 3;
    int ga = mBase + r; ga = ga < Mvalid ? ga : Mvalid - 1;
    int gb = nBase + r; gb = gb < Nvalid ? gb : Nvalid - 1;
    aSrc[j] = Ab + (size_t)ga * lda + gc;
    bSrc[j] = Bb + (size_t)gb * ldb + gc;
    ldsOff[j] = (wid_u * 32 + j * 8) * 128;
  }
  f32x4 acc[4][4] = {};

  auto STAGE = [&](int buf, int k0) {
    unsigned base = (unsigned)buf * 32768u;
#pragma unroll
    for (int j = 0; j < 4; ++j) {
      gload_lds16(aSrc[j] + k0, smem + base + ldsOff[j]);
      gload_lds16(bSrc[j] + k0, smem + base + 16384 + ldsOff[j]);
    }
  };

  const int nt = Kloop >> 6;
  STAGE(0, 0);
  __syncthreads();
  for (int t = 0; t < nt; ++t) {
    if (t + 1 < nt) STAGE((t + 1) & 1, (t + 1) << 6);
    const unsigned char* As = smem + (t & 1) * 32768;
    const unsigned char* Bs = As + 16384;
#pragma unroll
    for (int ks = 0; ks < 2; ++ks) {
      s16x8 af[4], bfr[4];
#pragma unroll
      for (int mi = 0; mi < 4; ++mi) {
        int r = wm * 64 + mi * 16 + li;
        af[mi] = *(const s16x8*)(const void*)(As + r * 128 + ((ks * 64 + lg * 16) ^ ((r & 7) << 4)));
      }
#pragma unroll
      for (int ni = 0; ni < 4; ++ni) {
        int c = wn * 64 + ni * 16 + li;
        bfr[ni] = *(const s16x8*)(const void*)(Bs + c * 128 + ((ks * 64 + lg * 16) ^ ((c & 7) << 4)));
      }
#pragma unroll
      for (int mi = 0; mi < 4; ++mi)
#pragma unroll
        for (int ni = 0; ni < 4; ++ni)
          acc[mi][ni] = __builtin_amdgcn_mfma_f32_16x16x32_bf16(af[mi], bfr[ni], acc[mi][ni], 0, 0, 0);
    }
    __syncthreads();
  }

  if constexpr (EPI == 0 || EPI == 4) {
    bool full = (mBase + 128 <= Mvalid) && (nBase + 128 <= Nvalid);
    if (full) {
#pragma unroll
      for (int ni = 0; ni < 4; ++ni) {
        int c = nBase + wn * 64 + ni * 16 + li;
        float bv = (EPI == 0) ? bias[c] : 0.f;
#pragma unroll
        for (int mi = 0; mi < 4; ++mi) {
#pragma unroll
          for (int rg = 0; rg < 4; ++rg) {
            int r = mBase + wm * 64 + mi * 16 + lg * 4 + rg;
            if constexpr (EPI == 0) {
              float v = fmaxf(acc[mi][ni][rg] + bv, 0.f);
              ((ushort*)o0)[(size_t)r * ldOut + c] = f2bf(v);
            } else {
              ((float*)o0)[(size_t)bz * ntiles + (size_t)r * ldOut + c] = acc[mi][ni][rg];
            }
          }
        }
      }
    } else {
#pragma unroll
      for (int mi = 0; mi < 4; ++mi)
#pragma unroll
        for (int ni = 0; ni < 4; ++ni) {
          int c = nBase + wn * 64 + ni * 16 + li;
#pragma unroll
          for (int rg = 0; rg < 4; ++rg) {
            int r = mBase + wm * 64 + mi * 16 + lg * 4 + rg;
            if (r < Mvalid && c < Nvalid) {
              if constexpr (EPI == 0) {
                float v = fmaxf(acc[mi][ni][rg] + bias[c], 0.f);
                ((ushort*)o0)[(size_t)r * ldOut + c] = f2bf(v);
              } else {
                ((float*)o0)[(size_t)bz * ntiles + (size_t)r * ldOut + c] = acc[mi][ni][rg];
              }
            }
          }
        }
    }
  } else if constexpr (EPI == 2) {
    __syncthreads();
    float* reds = (float*)(void*)smem;   // [128][2]
#pragma unroll
    for (int mi = 0; mi < 4; ++mi)
#pragma unroll
      for (int rg = 0; rg < 4; ++rg) {
        float s = fexp2(acc[mi][0][rg] * scale) + fexp2(acc[mi][1][rg] * scale) +
                  fexp2(acc[mi][2][rg] * scale) + fexp2(acc[mi][3][rg] * scale);
#pragma unroll
        for (int d = 1; d < 16; d <<= 1) s += __shfl_xor(s, d);
        int rl = wm * 64 + mi * 16 + lg * 4 + rg;
        if (li == 0) reds[rl * 2 + wn] = s;
      }
    __syncthreads();
    if (tid < 128) {
      size_t idx = (size_t)(mBase + tid) * ntiles + bx;
      ((float*)o0)[idx] = reds[tid * 2] + reds[tid * 2 + 1];
    }
  } else if constexpr (EPI == 3) {
    __syncthreads();
    float* redv = (float*)(void*)smem;
    int* redi = (int*)(void*)(smem + 1024);
#pragma unroll
    for (int mi = 0; mi < 4; ++mi)
#pragma unroll
      for (int rg = 0; rg < 4; ++rg) {
        float bv = -3.4e38f;
        int bi = 0x7fffffff;
#pragma unroll
        for (int ni = 0; ni < 4; ++ni) {
          int c = nBase + wn * 64 + ni * 16 + li;
          float v = (c < Nvalid) ? acc[mi][ni][rg] : -3.4e38f;
          if (v > bv || (v == bv && c < bi)) { bv = v; bi = c; }
        }
#pragma unroll
        for (int d = 1; d < 16; d <<= 1) {
          float ov = __shfl_xor(bv, d);
          int oi = __shfl_xor(bi, d);
          if (ov > bv || (ov == bv && oi < bi)) { bv = ov; bi = oi; }
        }
        int rl = wm * 64 + mi * 16 + lg * 4 + rg;
        if (li == 0) { redv[rl * 2 + wn] = bv; redi[rl * 2 + wn] = bi; }
      }
    __syncthreads();
    if (tid < 128) {
      int r = mBase + tid;
      if (r < Mvalid) {
        float v0 = redv[tid * 2], v1 = redv[tid * 2 + 1];
        int i0 = redi[tid * 2], i1 = redi[tid * 2 + 1];
        float v = v0; int bi2 = i0;
        if (v1 > v || (v1 == v && i1 < bi2)) { v = v1; bi2 = i1; }
        size_t idx = (size_t)(bz * Mvalid + r) * ntiles + bx;
        ((float*)o0)[idx] = v;
        ((int*)o1)[idx] = bi2;
      }
    }
  }
}

// ---------------- sum 4 K-slice partials + bias, l2-normalize ----------------
__global__ void k_l2n_rows(const float* __restrict__ part, const float* __restrict__ bias,
                           float* __restrict__ of, ushort* __restrict__ ob, int rows) {
  int row = blockIdx.x * 4 + (threadIdx.x >> 6);
  int lane = threadIdx.x & 63;
  if (row >= rows) return;
  size_t i0 = (size_t)row * 128 + lane;
  const size_t SL = 802816;
  float v0 = bias[lane]      + part[i0]      + part[SL + i0]      + part[2 * SL + i0]      + part[3 * SL + i0];
  float v1 = bias[lane + 64] + part[i0 + 64] + part[SL + i0 + 64] + part[2 * SL + i0 + 64] + part[3 * SL + i0 + 64];
  float ss = v0 * v0 + v1 * v1;
#pragma unroll
  for (int d = 1; d < 64; d <<= 1) ss += __shfl_xor(ss, d);
  float r = 1.0f / sqrtf(fmaxf(ss, 1e-12f));
  of[i0] = v0 * r;
  of[i0 + 64] = v1 * r;
  ob[i0] = f2bf(v0 * r);
  ob[i0 + 64] = f2bf(v1 * r);
}

// ---------------- argmax finalize + gather ----------------
__global__ void k_argmax_gather(const float* __restrict__ pval, const int* __restrict__ pidx,
                                const ushort* __restrict__ kd_bf, ushort* __restrict__ matched_bf,
                                int* __restrict__ idxf) {
  int n = blockIdx.x;
  int b = n / 784;
  float bv = pval[(size_t)n * 7];
  int bi = pidx[(size_t)n * 7];
#pragma unroll
  for (int t = 1; t < 7; ++t) {
    float v = pval[(size_t)n * 7 + t];
    int i2 = pidx[(size_t)n * 7 + t];
    if (v > bv) { bv = v; bi = i2; }
  }
  int lane = threadIdx.x;
  if (lane == 0) idxf[n] = bi;
  const ushort* src = kd_bf + (size_t)(b * 784 + bi) * 128;
  ushort* dst = matched_bf + (size_t)n * 128;
  dst[lane] = src[lane];
  dst[lane + 64] = src[lane + 64];
}

// ---------------- queue InfoNCE partials (max-free) ----------------
__global__ __launch_bounds__(256) void k_queue_nce(const float* __restrict__ queue,
                                                   const float* __restrict__ qg,
                                                   float* __restrict__ ps) {
  __shared__ float qs[1024];
  int tid = threadIdx.x;
  for (int i = tid; i < 1024; i += 256) qs[i] = qg[i];
  __syncthreads();
  int r = blockIdx.x * 256 + tid;
  const float* qr = queue + (size_t)r * 128;
  float a[8] = {0, 0, 0, 0, 0, 0, 0, 0};
  for (int j = 0; j < 128; j += 4) {
    float4 v = *(const float4*)(const void*)(qr + j);
#pragma unroll
    for (int b = 0; b < 8; ++b)
      a[b] += v.x * qs[b * 128 + j] + v.y * qs[b * 128 + j + 1] +
              v.z * qs[b * 128 + j + 2] + v.w * qs[b * 128 + j + 3];
  }
  __shared__ float lssum[8][4];
  int lane = tid & 63, w = tid >> 6;
#pragma unroll
  for (int b = 0; b < 8; ++b) {
    float s = fexp2(a[b] * (TAU_INV * L2E));
#pragma unroll
    for (int d = 1; d < 64; d <<= 1) s += __shfl_xor(s, d);
    if (lane == 0) lssum[b][w] = s;
  }
  __syncthreads();
  if (tid < 8) {
    int b = tid;
    ps[blockIdx.x * 8 + b] = lssum[b][0] + lssum[b][1] + lssum[b][2] + lssum[b][3];
  }
}

// ---------------- per-row: sum 49 partials -> log + pos dot ----------------
__global__ void k_row_lse(const float* __restrict__ psum, const int* __restrict__ idxf,
                          const float* __restrict__ qd, const float* __restrict__ kd,
                          float* __restrict__ diff) {
  int n = blockIdx.x * 4 + (threadIdx.x >> 6);
  int lane = threadIdx.x & 63;
  float s = (lane < 49) ? psum[(size_t)n * 49 + lane] : 0.f;
#pragma unroll
  for (int d = 1; d < 64; d <<= 1) s += __shfl_xor(s, d);
  int b = n / 784;
  int mr = b * 784 + idxf[n];
  float pos = qd[(size_t)n * 128 + lane] * kd[(size_t)mr * 128 + lane] +
              qd[(size_t)n * 128 + 64 + lane] * kd[(size_t)mr * 128 + 64 + lane];
#pragma unroll
  for (int d = 1; d < 64; d <<= 1) pos += __shfl_xor(pos, d);
  if (lane == 0) diff[n] = logf(s) - pos * TAU_INV;
}

// ---------------- final combine (max-free) ----------------
__global__ void k_final(const float* __restrict__ ps, const float* __restrict__ lpos,
                        const float* __restrict__ diff, float* __restrict__ out) {
  int tid = threadIdx.x;
  int lane = tid & 63, w = tid >> 6;
  __shared__ float sm[4];
  float lg = 0.f;
  for (int b = 0; b < 8; ++b) {
    float s = ps[tid * 8 + b];
#pragma unroll
    for (int d = 1; d < 64; d <<= 1) s += __shfl_xor(s, d);
    if (lane == 0) sm[w] = s;
    __syncthreads();
    if (tid == 0) {
      float S = sm[0] + sm[1] + sm[2] + sm[3];
      float lp = lpos[b] * TAU_INV;
      S += fexp2(lp * L2E);
      lg += logf(S) - lp;
    }
    __syncthreads();
  }
  float v = 0.f;
  for (int i = tid; i < 6272; i += 256) v += diff[i];
#pragma unroll
  for (int d = 1; d < 64; d <<= 1) v += __shfl_xor(v, d);
  if (lane == 0) sm[w] = v;
  __syncthreads();
  if (tid == 0) {
    float ld = sm[0] + sm[1] + sm[2] + sm[3];
    out[0] = 0.5f * (lg * 0.125f) + 0.5f * (ld * (1.0f / 6272.0f));
  }
}

extern "C" void kernel_launch(void* const* d_in, const int* in_sizes, int n_in,
                              void* d_out, int out_size, void* d_ws, size_t ws_size,
                              hipStream_t stream) {
  (void)in_sizes; (void)n_in; (void)out_size; (void)ws_size;
  const float* feat_q = (const float*)d_in[0];
  const float* feat_k = (const float*)d_in[1];
  const float* Wg1 = (const float*)d_in[2];
  const float* bg1 = (const float*)d_in[3];
  const float* Wg2 = (const float*)d_in[4];
  const float* bg2 = (const float*)d_in[5];
  const float* Wd1 = (const float*)d_in[6];
  const float* bd1 = (const float*)d_in[7];
  const float* Wd2 = (const float*)d_in[8];
  const float* bd2 = (const float*)d_in[9];
  const float* mWg1 = (const float*)d_in[10];
  const float* mbg1 = (const float*)d_in[11];
  const float* mWg2 = (const float*)d_in[12];
  const float* mbg2 = (const float*)d_in[13];
  const float* mWd1 = (const float*)d_in[14];
  const float* mbd1 = (const float*)d_in[15];
  const float* mWd2 = (const float*)d_in[16];
  const float* mbd2 = (const float*)d_in[17];
  const float* queue = (const float*)d_in[18];
  float* out = (float*)d_out;

  // allow 128KB dynamic LDS for the 256^2 kernel (idempotent, capture-safe host call)
  (void)hipFuncSetAttribute(reinterpret_cast<const void*>(&k_gemm256),
                            hipFuncAttributeMaxDynamicSharedMemorySize, 131072);

  char* ws = (char*)d_ws;
  size_t off = 0;
  auto alloc = [&](size_t bytes) -> void* {
    void* p = (void*)(ws + off);
    off += (bytes + 255) & ~(size_t)255;
    return p;
  };

  ushort* featq_bf = (ushort*)alloc(6272ull * 1024 * 2);
  ushort* featk_bf = (ushort*)alloc(6272ull * 1024 * 2);
  ushort* Wd1t = (ushort*)alloc(2048ull * 1024 * 2);
  ushort* mWd1t = (ushort*)alloc(2048ull * 1024 * 2);
  ushort* Wd2t = (ushort*)alloc(128ull * 2048 * 2);
  ushort* mWd2t = (ushort*)alloc(128ull * 2048 * 2);
  ushort* h_bf = (ushort*)alloc(6272ull * 2048 * 2);
  float* e2part = (float*)alloc(4ull * 6272 * 128 * 4);
  float* qd = (float*)alloc(6272ull * 128 * 4);
  float* kd = (float*)alloc(6272ull * 128 * 4);
  ushort* qd_bf = (ushort*)alloc(6272ull * 128 * 2);
  ushort* kd_bf = (ushort*)alloc(6272ull * 128 * 2);
  ushort* matched_bf = (ushort*)alloc(6272ull * 128 * 2);
  float* psum = (float*)alloc(6272ull * 49 * 4);
  float* pval = (float*)alloc(6272ull * 7 * 4);
  int* pidx = (int*)alloc(6272ull * 7 * 4);
  int* idxf = (int*)alloc(6272ull * 4);
  float* gpart = (float*)alloc(8ull * 112 * 1024 * 4);
  float* gq = (float*)alloc(8ull * 1024 * 4);
  float* gk = (float*)alloc(8ull * 1024 * 4);
  float* part1 = (float*)alloc(16ull * 8 * 2048 * 4);
  float* hgq = (float*)alloc(8ull * 2048 * 4);
  float* hgk = (float*)alloc(8ull * 2048 * 4);
  float* part2q = (float*)alloc(32ull * 8 * 128 * 4);
  float* part2k = (float*)alloc(32ull * 8 * 128 * 4);
  float* qg = (float*)alloc(8ull * 128 * 4);
  float* kg = (float*)alloc(8ull * 128 * 4);
  float* l_pos = (float*)alloc(8ull * 4);
  float* qpart_s = (float*)alloc(256ull * 8 * 4);
  float* diff = (float*)alloc(6272ull * 4);

  k_cvt_pool<<<dim3(112, 8), 256, 0, stream>>>(feat_q, featq_bf, gpart);
  k_gpool_fin<<<32, 256, 0, stream>>>(gpart, gq);
  k_cvt_pool<<<dim3(112, 8), 256, 0, stream>>>(feat_k, featk_bf, gpart);
  k_gpool_fin<<<32, 256, 0, stream>>>(gpart, gk);

  k_transpose_cvt<<<dim3(64, 32), 256, 0, stream>>>(Wd1, Wd1t, 1024, 2048);
  k_transpose_cvt<<<dim3(64, 32), 256, 0, stream>>>(mWd1, mWd1t, 1024, 2048);
  k_transpose_cvt<<<dim3(4, 64), 256, 0, stream>>>(Wd2, Wd2t, 2048, 128);
  k_transpose_cvt<<<dim3(4, 64), 256, 0, stream>>>(mWd2, mWd2t, 2048, 128);

  k_dense1_part<<<dim3(8, 16), 256, 0, stream>>>(gq, Wg1, part1);
  k_dense1_fin<<<64, 256, 0, stream>>>(part1, bg1, hgq);
  k_dense2_part<<<32, 128, 0, stream>>>(hgq, Wg2, part2q);
  k_dense1_part<<<dim3(8, 16), 256, 0, stream>>>(gk, mWg1, part1);
  k_dense1_fin<<<64, 256, 0, stream>>>(part1, mbg1, hgk);
  k_dense2_part<<<32, 128, 0, stream>>>(hgk, mWg2, part2k);
  k_head_fin<<<8, 64, 0, stream>>>(part2q, part2k, bg2, mbg2, qg, kg, l_pos);

  // E1 (256^2 8-wave): h = relu(feat @ Wd1 + bd1)
  k_gemm256<<<dim3(8, 25), 512, 131072, stream>>>(featq_bf, Wd1t, bd1, h_bf, 6272, 1024, 2048);
  k_gemm_abt<4><<<dim3(1, 49, 4), 256, 0, stream>>>(h_bf, Wd2t, nullptr, e2part, nullptr,
                                                    6272, 128, 512, 2048, 2048, 128, 802816, 0.f, 512, 512);
  k_l2n_rows<<<1568, 256, 0, stream>>>(e2part, bd2, qd, qd_bf, 6272);

  k_gemm256<<<dim3(8, 25), 512, 131072, stream>>>(featk_bf, mWd1t, mbd1, h_bf, 6272, 1024, 2048);
  k_gemm_abt<4><<<dim3(1, 49, 4), 256, 0, stream>>>(h_bf, mWd2t, nullptr, e2part, nullptr,
                                                    6272, 128, 512, 2048, 2048, 128, 802816, 0.f, 512, 512);
  k_l2n_rows<<<1568, 256, 0, stream>>>(e2part, mbd2, kd, kd_bf, 6272);

  k_gemm_abt<3><<<dim3(7, 7, 8), 256, 0, stream>>>(qd_bf, kd_bf, nullptr, pval, pidx,
                                                   784, 784, 128, 128, 128, 0, 7, 0.f,
                                                   784l * 128, 784l * 128);
  k_argmax_gather<<<6272, 64, 0, stream>>>(pval, pidx, kd_bf, matched_bf, idxf);

  k_gemm_abt<2><<<dim3(49, 49, 1), 256, 0, stream>>>(qd_bf, matched_bf, nullptr, psum, nullptr,
                                                     6272, 6272, 128, 128, 128, 0, 49,
                                                     TAU_INV * L2E, 0, 0);

  k_queue_nce<<<256, 256, 0, stream>>>(queue, qg, qpart_s);

  k_row_lse<<<1568, 256, 0, stream>>>(psum, idxf, qd, kd, diff);
  k_final<<<1, 256, 0, stream>>>(qpart_s, l_pos, diff, out);
}